// Round 4
// baseline (263.938 us; speedup 1.0000x reference)
//
#include <hip/hip_runtime.h>
#include <cstdint>

// Hierarchical classification head, R12 (= R8 structure, register-direct GEMM):
//   cast         : fp32 -> fp8 e4m3 X and W (W pre-scaled x16), bias fp32
//   gemm_sig     : Zb = sigmoid((Xq @ Wq^T)/16 + b) bf16; fp8 MFMA 16x16x32.
//                  NEW (R12): NO LDS, NO BARRIERS. Each lane loads its MFMA
//                  fragment (8 B) straight from global: lane (m=lane&15,
//                  u=lane>>4) reads row*H + kt*32 + u*8 -- the R7/R8 LDS
//                  swizzle net-mapped to exactly this, so staging was pure
//                  plumbing. Waves fully independent; compiler pipelines
//                  loads across K with no barrier to stop it. Per-XCD
//                  working set (A band 512 KB + B 3.2 MB) fits L2 via the
//                  R4 band swizzle, so these are L2 hits (~610 MB total,
//                  ~30 TB/s < 34.5 TB/s L2 ceiling).
//                  R11 post-mortem: 2-phase LDS prefetch = 43 us, MfmaUtil
//                  22%, bank-conflicts 4.9M -- barrier lockstep dominated.
//   logits_loss  : per-row logits3 -> d_out; ONLY 588 ancestor z in LDS,
//                  z3[k] streamed from global (R8, measured good)
//   final_reduce : 4096 partials -> mean loss scalar

typedef unsigned short u16;
typedef unsigned char u8;
typedef long i64;
typedef float f32x4 __attribute__((ext_vector_type(4)));

constexpr int BATCH = 4096;
constexpr int H     = 1024;
constexpr int N1 = 28, N2 = 280, N3 = 2800;
constexpr int NT = N1 + N2 + N3;   // 3108
constexpr int NP = 3200;           // 25 * 128
constexpr int NANC = N1 + N2 + 280;  // 588 ancestor values
constexpr float WSCALE = 16.0f;
constexpr float WINV   = 1.0f / 16.0f;

__device__ inline u16 f2bf(float f) {
    unsigned int u = __float_as_uint(f);
    u += 0x7fffu + ((u >> 16) & 1u);
    return (u16)(u >> 16);
}
__device__ inline float bf2f(unsigned int u) { return __uint_as_float(u << 16); }

__device__ inline unsigned int pk4_fp8(float a, float b, float c, float d) {
    unsigned int r = __builtin_amdgcn_cvt_pk_fp8_f32(a, b, 0, false);
    r = __builtin_amdgcn_cvt_pk_fp8_f32(c, d, (int)r, true);
    return r;
}

// ---------------- cast fp32 -> fp8 + fused bias ----------------
constexpr int XG = (BATCH * H) / 4;   // 1,048,576
constexpr int WG = (NP * H) / 4;      //   819,200
constexpr int BG = NP / 4;            //       800

__global__ __launch_bounds__(256) void cast_kernel(
        const float* __restrict__ x,
        const float* __restrict__ W1, const float* __restrict__ W2,
        const float* __restrict__ W3,
        const float* __restrict__ b1, const float* __restrict__ b2,
        const float* __restrict__ b3,
        u8* __restrict__ Xq, u8* __restrict__ Wq, float* __restrict__ biasf) {
    int g = blockIdx.x * 256 + threadIdx.x;
    if (g < XG) {
        float4 v = ((const float4*)x)[g];
        ((unsigned int*)Xq)[g] = pk4_fp8(v.x, v.y, v.z, v.w);
    } else if (g < XG + WG) {
        int wg = g - XG;
        int row = wg >> 8, cg = wg & 255;
        float4 v = make_float4(0.f, 0.f, 0.f, 0.f);
        if (row < N1)           v = ((const float4*)W1)[row * 256 + cg];
        else if (row < N1 + N2) v = ((const float4*)W2)[(row - N1) * 256 + cg];
        else if (row < NT)      v = ((const float4*)W3)[(row - N1 - N2) * 256 + cg];
        ((unsigned int*)Wq)[wg] = pk4_fp8(v.x * WSCALE, v.y * WSCALE, v.z * WSCALE, v.w * WSCALE);
    } else if (g < XG + WG + BG) {
        int bg = g - XG - WG;
        float4 v; float* vp = &v.x;
        #pragma unroll
        for (int i = 0; i < 4; ++i) {
            int c = bg * 4 + i; float t = 0.f;
            if (c < N1)           t = b1[c];
            else if (c < N1 + N2) t = b2[c - N1];
            else if (c < NT)      t = b3[c - N1 - N2];
            vp[i] = t;
        }
        ((float4*)biasf)[bg] = v;
    }
}

// ---------------- GEMM: Zb = sigmoid(acc/16 + bias), fp8 inputs, bf16 out ----------------
// 64x128 block tile, 4 waves 2x2 (wave = 32 rows x 64 cols). Register-direct:
// per K=32 panel each wave does 6 x global_load_dwordx2 (L2-hit) + 8 MFMA.
// No LDS, no __syncthreads in the whole kernel.
__global__ __launch_bounds__(256) void gemm_sig(
        const u8* __restrict__ Xq, const u8* __restrict__ Wq,
        const float* __restrict__ biasf, u16* __restrict__ Zb) {
    // XCD band swizzle: 64 m-tiles x 25 n-tiles; XCD owns 8-m-tile band.
    // Per-XCD working set: A band 512 KB + B stream 3.2 MB < 4 MB L2.
    const int id  = blockIdx.x;        // 0..1599
    const int xcd = id & 7;
    const int j   = id >> 3;           // 0..199
    const int m0 = ((xcd << 3) | (j & 7)) * 64;    // m-tile 0..63
    const int n0 = (j >> 3) * 128;                 // n-tile 0..24

    const int tid  = threadIdx.x;
    const int lane = tid & 63;
    const int wave = tid >> 6;
    const int wr = wave >> 1;          // m half (32 rows)
    const int wc = wave & 1;           // n half (64 cols)

    const int laneM = lane & 15;       // m/n within 16-tile
    const int u     = lane >> 4;       // k-group: lane supplies bytes k = u*8..u*8+7

    // fixed per-lane byte offsets into Xq / Wq (32-bit; saddr+voffset+imm loads)
    unsigned offA[2], offB[4];
    #pragma unroll
    for (int i = 0; i < 2; ++i)
        offA[i] = (unsigned)(m0 + wr * 32 + i * 16 + laneM) * H + u * 8;
    #pragma unroll
    for (int i = 0; i < 4; ++i)
        offB[i] = (unsigned)(n0 + wc * 64 + i * 16 + laneM) * H + u * 8;

    f32x4 acc[2][4] = {};

    #pragma unroll 4
    for (int kt = 0; kt < H / 32; ++kt) {          // 32 K-panels
        const int kb = kt * 32;
        i64 af[2], bfv[4];
        #pragma unroll
        for (int i = 0; i < 2; ++i)
            af[i]  = *(const i64*)(Xq + offA[i] + kb);
        #pragma unroll
        for (int i = 0; i < 4; ++i)
            bfv[i] = *(const i64*)(Wq + offB[i] + kb);
        #pragma unroll
        for (int am = 0; am < 2; ++am)
            #pragma unroll
            for (int bn = 0; bn < 4; ++bn)
                acc[am][bn] = __builtin_amdgcn_mfma_f32_16x16x32_fp8_fp8(
                    af[am], bfv[bn], acc[am][bn], 0, 0, 0);
    }

    // epilogue: C/D layout col = lane&15, row = (lane>>4)*4 + r; unscale, bf16 store
    #pragma unroll
    for (int bn = 0; bn < 4; ++bn) {
        const int col = n0 + wc * 64 + bn * 16 + laneM;
        if (col >= NT) continue;
        const float bias = biasf[col];
        #pragma unroll
        for (int am = 0; am < 2; ++am) {
            const int rbase = m0 + wr * 32 + am * 16 + u * 4;
            #pragma unroll
            for (int r = 0; r < 4; ++r) {
                float v = acc[am][bn][r] * WINV + bias;
                Zb[(size_t)(rbase + r) * NP + col] = f2bf(1.0f / (1.0f + __expf(-v)));
            }
        }
    }
}

// ---------------- per-row logits + CE partial (no atomic) ----------------
// LDS holds only the 588 ancestor z (z1|z2|z3[0:280)); z3[k] streamed global.
__global__ __launch_bounds__(256) void logits_loss(
        const u16* __restrict__ Zb, const int* __restrict__ labels,
        float* __restrict__ out, float* __restrict__ partials) {
    __shared__ float zs[NANC];             // [0,28) z1 | [28,308) z2 | [308,588) z3[0:280)
    __shared__ float red[12];
    const int b = blockIdx.x, tid = threadIdx.x;
    const u16* Zrow = Zb + (size_t)b * NP;

    const unsigned int* Zr = (const unsigned int*)Zrow;
    for (int i = tid; i < NANC / 2; i += 256) {    // 294 uints
        unsigned int v = Zr[i];
        zs[2 * i]     = bf2f(v & 0xffffu);
        zs[2 * i + 1] = bf2f(v >> 16);
    }
    __syncthreads();

    float se1 = 0.f, se2 = 0.f, se3 = 0.f;
    float4* outr4 = (float4*)(out + (size_t)b * N3);
    // z3 block starts at element 308 (uint index 154, even -> uint2-aligned)
    const uint2* Z3s = (const uint2*)(Zrow + N1 + N2);
    for (int q = tid; q < N3 / 4; q += 256) {
        const uint2 zv = Z3s[q];               // z3[4q..4q+3]
        float z3v[4] = { bf2f(zv.x & 0xffffu), bf2f(zv.x >> 16),
                         bf2f(zv.y & 0xffffu), bf2f(zv.y >> 16) };
        const int k = q * 4;
        float4 o; float* op = &o.x;
        #pragma unroll
        for (int uu = 0; uu < 4; ++uu) {
            const int kk = k + uu;
            float lg = z3v[uu] * zs[308 + kk / 10] * zs[308 + kk / 100];
            op[uu] = lg;
            se3 += __expf(lg);
        }
        outr4[q] = o;
    }
    for (int jj = tid; jj < N2; jj += 256)
        se2 += __expf(zs[N1 + jj] * zs[N1 + jj / 10]);
    if (tid < N1)
        se1 = __expf(zs[tid]);

    #pragma unroll
    for (int off = 32; off > 0; off >>= 1) {
        se1 += __shfl_down(se1, off, 64);
        se2 += __shfl_down(se2, off, 64);
        se3 += __shfl_down(se3, off, 64);
    }
    if ((tid & 63) == 0) {
        int w = tid >> 6;
        red[w] = se3; red[4 + w] = se2; red[8 + w] = se1;
    }
    __syncthreads();
    if (tid == 0) {
        float s3 = red[0] + red[1] + red[2] + red[3];
        float s2 = red[4] + red[5] + red[6] + red[7];
        float s1 = red[8] + red[9] + red[10] + red[11];
        int lab  = labels[b];
        int lab2 = lab / 10, lab1 = lab / 100;
        float l1 = zs[lab1];
        float l2 = zs[N1 + lab2] * zs[N1 + lab2 / 10];
        float l3 = bf2f((unsigned int)Zrow[N1 + N2 + lab]) * zs[308 + lab2] * zs[308 + lab1];
        partials[b] = (logf(s1) - l1) + (logf(s2) - l2) + (logf(s3) - l3);
    }
}

// ---------------- final loss reduce ----------------
__global__ __launch_bounds__(256) void final_reduce(
        const float* __restrict__ partials, float* __restrict__ out) {
    __shared__ float red[4];
    const int tid = threadIdx.x;
    float s = 0.f;
    for (int i = tid; i < BATCH; i += 256) s += partials[i];
    #pragma unroll
    for (int off = 32; off > 0; off >>= 1) s += __shfl_down(s, off, 64);
    if ((tid & 63) == 0) red[tid >> 6] = s;
    __syncthreads();
    if (tid == 0)
        out[(size_t)BATCH * N3] = (red[0] + red[1] + red[2] + red[3]) * (1.0f / BATCH);
}

extern "C" void kernel_launch(void* const* d_in, const int* in_sizes, int n_in,
                              void* d_out, int out_size, void* d_ws, size_t ws_size,
                              hipStream_t stream) {
    const float* x      = (const float*)d_in[0];
    const int*   labels = (const int*)d_in[1];
    const float* W1     = (const float*)d_in[2];
    const float* b1     = (const float*)d_in[3];
    const float* W2     = (const float*)d_in[4];
    const float* b2     = (const float*)d_in[5];
    const float* W3     = (const float*)d_in[6];
    const float* b3     = (const float*)d_in[7];
    float* out = (float*)d_out;

    char* ws = (char*)d_ws;
    u8*    Xq       = (u8*)ws;                     //  4,194,304 B  [4096][1024] fp8
    u8*    Wq       = (u8*)(ws + 4194304);         //  3,276,800 B  [3200][1024] fp8
    u16*   Zb       = (u16*)(ws + 7471104);        // 26,214,400 B  [4096][3200] bf16
    float* biasf    = (float*)(ws + 33685504);     //     12,800 B
    float* partials = (float*)(ws + 33698304);     //     16,384 B
    // total ws use: 33,714,688 B

    cast_kernel<<<(XG + WG + BG + 255) / 256, 256, 0, stream>>>(
        x, W1, W2, W3, b1, b2, b3, Xq, Wq, biasf);
    gemm_sig<<<1600, 256, 0, stream>>>(Xq, Wq, biasf, Zb);
    logits_loss<<<BATCH, 256, 0, stream>>>(Zb, labels, out, partials);
    final_reduce<<<1, 256, 0, stream>>>(partials, out);
}

// Round 5
// 148.672 us; speedup vs baseline: 1.7753x; 1.7753x over previous
//
#include <hip/hip_runtime.h>
#include <cstdint>

// Hierarchical classification head, R13 (= R11 + counted-vmcnt barriers, T4):
//   cast         : fp32 -> fp8 e4m3 X and W (W pre-scaled x16), bias fp32
//   gemm_sig     : Zb = sigmoid((Xq @ Wq^T)/16 + b) bf16; fp8 MFMA 16x16x32.
//                  BK=64 double-buffered prefetch (R11) -- but barriers are
//                  now raw s_barrier + inline-asm s_waitcnt vmcnt(3): the 3
//                  next-tile global_load_lds stay IN FLIGHT across both
//                  barriers instead of being drained by __syncthreads'
//                  vmcnt(0) (m218: counted-vs-drain was the +38-73% lever).
//                  sched_barrier(0) after each wait+barrier pins ds_reads
//                  (rule #18). Write-after-read safe: buffer b overwritten
//                  only after the barrier following all reads of b.
//                  R12 post-mortem: register-direct (no LDS) = 157 us --
//                  16-row scatter per load, L2-latency bound; reverted.
//   logits_loss  : per-row logits3 -> d_out; ONLY 588 ancestor z in LDS,
//                  z3[k] streamed from global (R8, measured good)
//   final_reduce : 4096 partials -> mean loss scalar

typedef unsigned short u16;
typedef unsigned char u8;
typedef long i64;
typedef float f32x4 __attribute__((ext_vector_type(4)));

#define AS_G __attribute__((address_space(1)))
#define AS_L __attribute__((address_space(3)))

constexpr int BATCH = 4096;
constexpr int H     = 1024;
constexpr int N1 = 28, N2 = 280, N3 = 2800;
constexpr int NT = N1 + N2 + N3;   // 3108
constexpr int NP = 3200;           // 25 * 128
constexpr int NANC = N1 + N2 + 280;  // 588 ancestor values
constexpr float WSCALE = 16.0f;
constexpr float WINV   = 1.0f / 16.0f;

__device__ inline u16 f2bf(float f) {
    unsigned int u = __float_as_uint(f);
    u += 0x7fffu + ((u >> 16) & 1u);
    return (u16)(u >> 16);
}
__device__ inline float bf2f(unsigned int u) { return __uint_as_float(u << 16); }

__device__ inline unsigned int pk4_fp8(float a, float b, float c, float d) {
    unsigned int r = __builtin_amdgcn_cvt_pk_fp8_f32(a, b, 0, false);
    r = __builtin_amdgcn_cvt_pk_fp8_f32(c, d, (int)r, true);
    return r;
}

// ---------------- cast fp32 -> fp8 + fused bias ----------------
constexpr int XG = (BATCH * H) / 4;   // 1,048,576
constexpr int WG = (NP * H) / 4;      //   819,200
constexpr int BG = NP / 4;            //       800

__global__ __launch_bounds__(256) void cast_kernel(
        const float* __restrict__ x,
        const float* __restrict__ W1, const float* __restrict__ W2,
        const float* __restrict__ W3,
        const float* __restrict__ b1, const float* __restrict__ b2,
        const float* __restrict__ b3,
        u8* __restrict__ Xq, u8* __restrict__ Wq, float* __restrict__ biasf) {
    int g = blockIdx.x * 256 + threadIdx.x;
    if (g < XG) {
        float4 v = ((const float4*)x)[g];
        ((unsigned int*)Xq)[g] = pk4_fp8(v.x, v.y, v.z, v.w);
    } else if (g < XG + WG) {
        int wg = g - XG;
        int row = wg >> 8, cg = wg & 255;
        float4 v = make_float4(0.f, 0.f, 0.f, 0.f);
        if (row < N1)           v = ((const float4*)W1)[row * 256 + cg];
        else if (row < N1 + N2) v = ((const float4*)W2)[(row - N1) * 256 + cg];
        else if (row < NT)      v = ((const float4*)W3)[(row - N1 - N2) * 256 + cg];
        ((unsigned int*)Wq)[wg] = pk4_fp8(v.x * WSCALE, v.y * WSCALE, v.z * WSCALE, v.w * WSCALE);
    } else if (g < XG + WG + BG) {
        int bg = g - XG - WG;
        float4 v; float* vp = &v.x;
        #pragma unroll
        for (int i = 0; i < 4; ++i) {
            int c = bg * 4 + i; float t = 0.f;
            if (c < N1)           t = b1[c];
            else if (c < N1 + N2) t = b2[c - N1];
            else if (c < NT)      t = b3[c - N1 - N2];
            vp[i] = t;
        }
        ((float4*)biasf)[bg] = v;
    }
}

// ---------------- GEMM: Zb = sigmoid(acc/16 + bias), fp8 inputs, bf16 out ----------------
// 64x128 tile, BK=64, double-buffered prefetch, 16 iters, 4 waves 2x2.
// LDS 2*(4+8) KB = 24 KB -> 6 blocks/CU resource-fit (same as R8/R11).
// Counted-vmcnt protocol: per iter {STAGE(next); vmcnt(3); barrier;
// compute(cur); barrier} -- next-tile loads never drained.
__global__ __launch_bounds__(256) void gemm_sig(
        const u8* __restrict__ Xq, const u8* __restrict__ Wq,
        const float* __restrict__ biasf, u16* __restrict__ Zb) {
    __shared__ __align__(16) u8 As[2][2 * 64 * 32];    // 4 KB per buffer
    __shared__ __align__(16) u8 Bs[2][2 * 128 * 32];   // 8 KB per buffer

    // XCD band swizzle: 64 m-tiles x 25 n-tiles; XCD owns 8-m-tile band.
    const int id  = blockIdx.x;        // 0..1599
    const int xcd = id & 7;
    const int j   = id >> 3;           // 0..199
    const int m0 = ((xcd << 3) | (j & 7)) * 64;    // m-tile 0..63
    const int n0 = (j >> 3) * 128;                 // n-tile 0..24

    const int tid  = threadIdx.x;
    const int lane = tid & 63;
    const int wave = tid >> 6;
    const int wr = wave >> 1;          // m half (32 rows)
    const int wc = wave & 1;           // n half (64 cols)

    const int laneM = lane & 15;
    // 16B-rotation swizzle (R7): unit index = (u>>1) ^ ((row>>2)&1)
    const int u   = lane >> 4;
    const int xb  = (laneM >> 2) & 1;
    const int laneKb = (((u >> 1) ^ xb) << 4) + (u & 1) * 8;

    // A staging: 256 chunks (16B), 1/thread. chunk c: panel=c>>7, rem=c&127,
    // row=rem>>1, v=rem&1.
    const int ac = tid;
    const int apanel = ac >> 7, arem = ac & 127;
    const int arowi = arem >> 1, av = arem & 1;
    const int agoff = apanel * 32 + ((av ^ ((arowi >> 2) & 1)) << 4);
    // B staging: 512 chunks, 2/thread.
    int brow[2], bgoff[2];
    #pragma unroll
    for (int t = 0; t < 2; ++t) {
        const int c = tid + 256 * t;
        const int panel = c >> 8, rem = c & 255;
        const int row = rem >> 1, v = rem & 1;
        brow[t]  = row;
        bgoff[t] = panel * 32 + ((v ^ ((row >> 2) & 1)) << 4);
    }

    auto STAGE = [&](int bufi, int kt) {       // 3 global_load_lds / thread
        const int k0 = kt * 64;
        __builtin_amdgcn_global_load_lds(
            (const AS_G uint32_t*)(Xq + (size_t)(m0 + arowi) * H + k0 + agoff),
            (AS_L uint32_t*)&As[bufi][ac * 16], 16, 0, 0);
        #pragma unroll
        for (int t = 0; t < 2; ++t) {
            const int c = tid + 256 * t;
            __builtin_amdgcn_global_load_lds(
                (const AS_G uint32_t*)(Wq + (size_t)(n0 + brow[t]) * H + k0 + bgoff[t]),
                (AS_L uint32_t*)&Bs[bufi][c * 16], 16, 0, 0);
        }
    };

    f32x4 acc[2][4] = {};

    STAGE(0, 0);
    int buf = 0;
    for (int kt = 0; kt < H / 64; ++kt) {          // 16 iterations
        if (kt + 1 < H / 64) {
            STAGE(buf ^ 1, kt + 1);                // next tile: stays in flight
            asm volatile("s_waitcnt vmcnt(3)" ::: "memory");   // cur tile landed
        } else {
            asm volatile("s_waitcnt vmcnt(0)" ::: "memory");
        }
        __builtin_amdgcn_s_barrier();              // all waves see cur tile
        __builtin_amdgcn_sched_barrier(0);         // pin ds_reads below (rule #18)

        #pragma unroll
        for (int p = 0; p < 2; ++p) {               // 2 k-panels of 32
            i64 af[2], bfv[4];
            #pragma unroll
            for (int i = 0; i < 2; ++i)
                af[i]  = *(const i64*)&As[buf][p * 2048 + (wr * 32 + i * 16 + laneM) * 32 + laneKb];
            #pragma unroll
            for (int i = 0; i < 4; ++i)
                bfv[i] = *(const i64*)&Bs[buf][p * 4096 + (wc * 64 + i * 16 + laneM) * 32 + laneKb];
            #pragma unroll
            for (int am = 0; am < 2; ++am)
                #pragma unroll
                for (int bn = 0; bn < 4; ++bn)
                    acc[am][bn] = __builtin_amdgcn_mfma_f32_16x16x32_fp8_fp8(
                        af[am], bfv[bn], acc[am][bn], 0, 0, 0);
        }
        __builtin_amdgcn_sched_barrier(0);         // keep reads above barrier
        __builtin_amdgcn_s_barrier();              // all reads of buf done
        buf ^= 1;
    }

    // epilogue: C/D layout col = lane&15, row = (lane>>4)*4 + r; unscale, bf16 store
    #pragma unroll
    for (int bn = 0; bn < 4; ++bn) {
        const int col = n0 + wc * 64 + bn * 16 + laneM;
        if (col >= NT) continue;
        const float bias = biasf[col];
        #pragma unroll
        for (int am = 0; am < 2; ++am) {
            const int rbase = m0 + wr * 32 + am * 16 + (lane >> 4) * 4;
            #pragma unroll
            for (int r = 0; r < 4; ++r) {
                float v = acc[am][bn][r] * WINV + bias;
                Zb[(size_t)(rbase + r) * NP + col] = f2bf(1.0f / (1.0f + __expf(-v)));
            }
        }
    }
}

// ---------------- per-row logits + CE partial (no atomic) ----------------
// LDS holds only the 588 ancestor z (z1|z2|z3[0:280)); z3[k] streamed global.
__global__ __launch_bounds__(256) void logits_loss(
        const u16* __restrict__ Zb, const int* __restrict__ labels,
        float* __restrict__ out, float* __restrict__ partials) {
    __shared__ float zs[NANC];             // [0,28) z1 | [28,308) z2 | [308,588) z3[0:280)
    __shared__ float red[12];
    const int b = blockIdx.x, tid = threadIdx.x;
    const u16* Zrow = Zb + (size_t)b * NP;

    const unsigned int* Zr = (const unsigned int*)Zrow;
    for (int i = tid; i < NANC / 2; i += 256) {    // 294 uints
        unsigned int v = Zr[i];
        zs[2 * i]     = bf2f(v & 0xffffu);
        zs[2 * i + 1] = bf2f(v >> 16);
    }
    __syncthreads();

    float se1 = 0.f, se2 = 0.f, se3 = 0.f;
    float4* outr4 = (float4*)(out + (size_t)b * N3);
    // z3 block starts at element 308 (uint index 154, even -> uint2-aligned)
    const uint2* Z3s = (const uint2*)(Zrow + N1 + N2);
    for (int q = tid; q < N3 / 4; q += 256) {
        const uint2 zv = Z3s[q];               // z3[4q..4q+3]
        float z3v[4] = { bf2f(zv.x & 0xffffu), bf2f(zv.x >> 16),
                         bf2f(zv.y & 0xffffu), bf2f(zv.y >> 16) };
        const int k = q * 4;
        float4 o; float* op = &o.x;
        #pragma unroll
        for (int uu = 0; uu < 4; ++uu) {
            const int kk = k + uu;
            float lg = z3v[uu] * zs[308 + kk / 10] * zs[308 + kk / 100];
            op[uu] = lg;
            se3 += __expf(lg);
        }
        outr4[q] = o;
    }
    for (int jj = tid; jj < N2; jj += 256)
        se2 += __expf(zs[N1 + jj] * zs[N1 + jj / 10]);
    if (tid < N1)
        se1 = __expf(zs[tid]);

    #pragma unroll
    for (int off = 32; off > 0; off >>= 1) {
        se1 += __shfl_down(se1, off, 64);
        se2 += __shfl_down(se2, off, 64);
        se3 += __shfl_down(se3, off, 64);
    }
    if ((tid & 63) == 0) {
        int w = tid >> 6;
        red[w] = se3; red[4 + w] = se2; red[8 + w] = se1;
    }
    __syncthreads();
    if (tid == 0) {
        float s3 = red[0] + red[1] + red[2] + red[3];
        float s2 = red[4] + red[5] + red[6] + red[7];
        float s1 = red[8] + red[9] + red[10] + red[11];
        int lab  = labels[b];
        int lab2 = lab / 10, lab1 = lab / 100;
        float l1 = zs[lab1];
        float l2 = zs[N1 + lab2] * zs[N1 + lab2 / 10];
        float l3 = bf2f((unsigned int)Zrow[N1 + N2 + lab]) * zs[308 + lab2] * zs[308 + lab1];
        partials[b] = (logf(s1) - l1) + (logf(s2) - l2) + (logf(s3) - l3);
    }
}

// ---------------- final loss reduce ----------------
__global__ __launch_bounds__(256) void final_reduce(
        const float* __restrict__ partials, float* __restrict__ out) {
    __shared__ float red[4];
    const int tid = threadIdx.x;
    float s = 0.f;
    for (int i = tid; i < BATCH; i += 256) s += partials[i];
    #pragma unroll
    for (int off = 32; off > 0; off >>= 1) s += __shfl_down(s, off, 64);
    if ((tid & 63) == 0) red[tid >> 6] = s;
    __syncthreads();
    if (tid == 0)
        out[(size_t)BATCH * N3] = (red[0] + red[1] + red[2] + red[3]) * (1.0f / BATCH);
}

extern "C" void kernel_launch(void* const* d_in, const int* in_sizes, int n_in,
                              void* d_out, int out_size, void* d_ws, size_t ws_size,
                              hipStream_t stream) {
    const float* x      = (const float*)d_in[0];
    const int*   labels = (const int*)d_in[1];
    const float* W1     = (const float*)d_in[2];
    const float* b1     = (const float*)d_in[3];
    const float* W2     = (const float*)d_in[4];
    const float* b2     = (const float*)d_in[5];
    const float* W3     = (const float*)d_in[6];
    const float* b3     = (const float*)d_in[7];
    float* out = (float*)d_out;

    char* ws = (char*)d_ws;
    u8*    Xq       = (u8*)ws;                     //  4,194,304 B  [4096][1024] fp8
    u8*    Wq       = (u8*)(ws + 4194304);         //  3,276,800 B  [3200][1024] fp8
    u16*   Zb       = (u16*)(ws + 7471104);        // 26,214,400 B  [4096][3200] bf16
    float* biasf    = (float*)(ws + 33685504);     //     12,800 B
    float* partials = (float*)(ws + 33698304);     //     16,384 B
    // total ws use: 33,714,688 B

    cast_kernel<<<(XG + WG + BG + 255) / 256, 256, 0, stream>>>(
        x, W1, W2, W3, b1, b2, b3, Xq, Wq, biasf);
    gemm_sig<<<1600, 256, 0, stream>>>(Xq, Wq, biasf, Zb);
    logits_loss<<<BATCH, 256, 0, stream>>>(Zb, labels, out, partials);
    final_reduce<<<1, 256, 0, stream>>>(partials, out);
}